// Round 4
// baseline (75.939 us; speedup 1.0000x reference)
//
#include <hip/hip_runtime.h>

// Separable cubic-B-spline coefficient->value filter:
// out = F_D(F_H(F_W(coeff))) with 3-tap [1/6, 4/6, 1/6], zero padding.
// Shape: (B*C=4, D=160, H=192, W=160), fp32.

static constexpr int Dd = 160;
static constexpr int Hh = 192;
static constexpr int Ww = 160;
static constexpr int BC = 4;

static constexpr float KW1 = 1.0f / 6.0f;
static constexpr float KW0 = 2.0f / 3.0f;

// Each thread: 2 z-outputs x 8 w-outputs at one (bc, z0..z0+1, y, w0..w0+7).
// Grid decomposition (fastest to slowest): wc(20), y(192), zp(80), bc(4).
__global__ __launch_bounds__(256) void CoeffToValue_kernel(
    const float* __restrict__ in, float* __restrict__ out)
{
    const int idx = blockIdx.x * 256 + threadIdx.x;
    const int wc = idx % 20;
    const int r1 = idx / 20;
    const int y  = r1 % Hh;
    const int r2 = r1 / Hh;
    const int zp = r2 % 80;
    const int bc = r2 / 80;
    if (bc >= BC) return;

    const int z0 = zp * 2;       // first of the two z outputs
    const int w0 = wc * 8;       // first of the eight w outputs

    // t{0,1}[j] = zy-filtered value at w = w0-1+j for output z0 / z0+1
    float t0[10], t1[10];
#pragma unroll
    for (int j = 0; j < 10; ++j) { t0[j] = 0.0f; t1[j] = 0.0f; }

    const float cw[3] = {KW1, KW0, KW1};

    // Input slices z0-1 .. z0+2 feed both z-outputs (z-filter taps).
#pragma unroll
    for (int ds = -1; ds <= 2; ++ds) {
        const int zs = z0 + ds;
        if (zs < 0 || zs >= Dd) continue;   // bound='zero'
#pragma unroll
        for (int dy = -1; dy <= 1; ++dy) {
            const int ys = y + dy;
            if (ys < 0 || ys >= Hh) continue;  // bound='zero'
            const float cy = cw[dy + 1];
            const float* row =
                in + (((size_t)bc * Dd + zs) * Hh + ys) * Ww + w0;

            // 10 input values: w0-1 .. w0+8 (zero at w edges)
            float v[10];
            v[0] = (w0 > 0) ? row[-1] : 0.0f;
            const float4 a = *reinterpret_cast<const float4*>(row);
            const float4 b = *reinterpret_cast<const float4*>(row + 4);
            v[1] = a.x; v[2] = a.y; v[3] = a.z; v[4] = a.w;
            v[5] = b.x; v[6] = b.y; v[7] = b.z; v[8] = b.w;
            v[9] = (w0 + 8 < Ww) ? row[8] : 0.0f;

            if (ds <= 1) {                       // z-tap for output z0
                const float c0 = cw[ds + 1] * cy;
#pragma unroll
                for (int j = 0; j < 10; ++j) t0[j] = fmaf(c0, v[j], t0[j]);
            }
            if (ds >= 0) {                       // z-tap for output z0+1
                const float c1 = cw[ds] * cy;
#pragma unroll
                for (int j = 0; j < 10; ++j) t1[j] = fmaf(c1, v[j], t1[j]);
            }
        }
    }

    // w-filter in registers, then two aligned float4 stores per z-output.
    float o0[8], o1[8];
#pragma unroll
    for (int i = 0; i < 8; ++i) {
        o0[i] = fmaf(KW1, t0[i], fmaf(KW0, t0[i + 1], KW1 * t0[i + 2]));
        o1[i] = fmaf(KW1, t1[i], fmaf(KW0, t1[i + 1], KW1 * t1[i + 2]));
    }

    float* orow0 = out + (((size_t)bc * Dd + z0) * Hh + y) * Ww + w0;
    float* orow1 = orow0 + (size_t)Hh * Ww;
    *reinterpret_cast<float4*>(orow0)     = make_float4(o0[0], o0[1], o0[2], o0[3]);
    *reinterpret_cast<float4*>(orow0 + 4) = make_float4(o0[4], o0[5], o0[6], o0[7]);
    *reinterpret_cast<float4*>(orow1)     = make_float4(o1[0], o1[1], o1[2], o1[3]);
    *reinterpret_cast<float4*>(orow1 + 4) = make_float4(o1[4], o1[5], o1[6], o1[7]);
}

extern "C" void kernel_launch(void* const* d_in, const int* in_sizes, int n_in,
                              void* d_out, int out_size, void* d_ws, size_t ws_size,
                              hipStream_t stream) {
    const float* in = (const float*)d_in[0];
    float* out = (float*)d_out;

    // total threads = 4 (bc) * 80 (z-pairs) * 192 (y) * 20 (w-chunks)
    const int total  = BC * (Dd / 2) * Hh * (Ww / 8);   // 1,228,800
    const int blocks = total / 256;                     // 4800
    CoeffToValue_kernel<<<blocks, 256, 0, stream>>>(in, out);
}

// Round 5
// 74.211 us; speedup vs baseline: 1.0233x; 1.0233x over previous
//
#include <hip/hip_runtime.h>

// Separable cubic-B-spline coefficient->value filter:
// out = F_D(F_H(F_W(coeff))) with 3-tap [1/6, 4/6, 1/6], zero padding.
// Shape: (B*C=4, D=160, H=192, W=160), fp32.
//
// Latency-bound fix vs R4: branchless load phase (clamped addresses,
// boundary zeroing folded into tap weights) so all 48 loads per thread
// issue back-to-back; high VGPR budget is intentional (MLP > occupancy).

typedef float f32x4 __attribute__((ext_vector_type(4)));

static constexpr int Dd = 160;
static constexpr int Hh = 192;
static constexpr int Ww = 160;
static constexpr int BC = 4;

static constexpr float KW1 = 1.0f / 6.0f;
static constexpr float KW0 = 2.0f / 3.0f;

// Each thread: 2 z-outputs x 8 w-outputs at (bc, z0..z0+1, y, w0..w0+7).
// Grid decomposition (fastest to slowest): wc(20), y(192), zp(80), bc(4).
__global__ __launch_bounds__(256, 2) void CoeffToValue_kernel(
    const float* __restrict__ in, float* __restrict__ out)
{
    const int idx = blockIdx.x * 256 + threadIdx.x;
    const int wc = idx % 20;
    const int r1 = idx / 20;
    const int y  = r1 % Hh;
    const int r2 = r1 / Hh;
    const int zp = r2 % 80;
    const int bc = r2 / 80;

    const int z0 = zp * 2;       // first of the two z outputs
    const int w0 = wc * 8;       // first of the eight w outputs

    // --- boundary handling: clamp addresses, zero the WEIGHTS for OOB taps ---
    int zrow[4];                 // clamped zs * Hh, for zs = z0-1 .. z0+2
    float cz0[4], cz1[4];        // z-tap weight for output z0 / z0+1 (0 if OOB)
    {
        const float wz0[4] = {KW1, KW0, KW1, 0.0f};
        const float wz1[4] = {0.0f, KW1, KW0, KW1};
#pragma unroll
        for (int ds = 0; ds < 4; ++ds) {
            int zs = z0 + ds - 1;
            const float ok = (zs >= 0 && zs < Dd) ? 1.0f : 0.0f;
            zs = zs < 0 ? 0 : (zs >= Dd ? Dd - 1 : zs);
            zrow[ds] = zs * Hh;
            cz0[ds] = wz0[ds] * ok;
            cz1[ds] = wz1[ds] * ok;
        }
    }
    int yrow[3];
    float cyw[3];                // y-tap weight (0 if OOB)
    {
        const float wy[3] = {KW1, KW0, KW1};
#pragma unroll
        for (int dy = 0; dy < 3; ++dy) {
            int ys = y + dy - 1;
            const float ok = (ys >= 0 && ys < Hh) ? 1.0f : 0.0f;
            ys = ys < 0 ? 0 : (ys >= Hh ? Hh - 1 : ys);
            yrow[dy] = ys;
            cyw[dy] = wy[dy] * ok;
        }
    }

    const float* basep = in + (size_t)bc * Dd * Hh * Ww + w0;
    const int offL = (w0 > 0) ? -1 : 0;       // clamped edge-load offsets
    const int offR = (w0 + 8 < Ww) ? 8 : 7;

    // --- Phase 1: issue ALL 12 row loads (2x float4 + 2 scalars each) ---
    f32x4 va[12], vb[12];
    float vl[12], vr[12];
#pragma unroll
    for (int ds = 0; ds < 4; ++ds) {
#pragma unroll
        for (int dy = 0; dy < 3; ++dy) {
            const int s = ds * 3 + dy;
            const float* row = basep + (size_t)(zrow[ds] + yrow[dy]) * Ww;
            va[s] = *reinterpret_cast<const f32x4*>(row);
            vb[s] = *reinterpret_cast<const f32x4*>(row + 4);
            vl[s] = row[offL];
            vr[s] = row[offR];
        }
    }

    // --- Phase 2: accumulate zy-filtered row t{0,1}[10] ---
    const float mL = (w0 > 0) ? 1.0f : 0.0f;        // w-edge zeroing masks
    const float mR = (w0 + 8 < Ww) ? 1.0f : 0.0f;
    float t0[10], t1[10];
#pragma unroll
    for (int j = 0; j < 10; ++j) { t0[j] = 0.0f; t1[j] = 0.0f; }

#pragma unroll
    for (int ds = 0; ds < 4; ++ds) {
#pragma unroll
        for (int dy = 0; dy < 3; ++dy) {
            const int s = ds * 3 + dy;
            const float c0 = cz0[ds] * cyw[dy];
            const float c1 = cz1[ds] * cyw[dy];
            float v[10];
            v[0] = vl[s] * mL;
            v[9] = vr[s] * mR;
#pragma unroll
            for (int k = 0; k < 4; ++k) {
                v[1 + k] = va[s][k];
                v[5 + k] = vb[s][k];
            }
#pragma unroll
            for (int j = 0; j < 10; ++j) {
                t0[j] = fmaf(c0, v[j], t0[j]);
                t1[j] = fmaf(c1, v[j], t1[j]);
            }
        }
    }

    // --- w-filter in registers, nontemporal float4 stores ---
    f32x4 o0a, o0b, o1a, o1b;
#pragma unroll
    for (int i = 0; i < 4; ++i) {
        o0a[i] = fmaf(KW1, t0[i],     fmaf(KW0, t0[i + 1], KW1 * t0[i + 2]));
        o0b[i] = fmaf(KW1, t0[i + 4], fmaf(KW0, t0[i + 5], KW1 * t0[i + 6]));
        o1a[i] = fmaf(KW1, t1[i],     fmaf(KW0, t1[i + 1], KW1 * t1[i + 2]));
        o1b[i] = fmaf(KW1, t1[i + 4], fmaf(KW0, t1[i + 5], KW1 * t1[i + 6]));
    }

    float* orow0 = out + (((size_t)bc * Dd + z0) * Hh + y) * Ww + w0;
    float* orow1 = orow0 + (size_t)Hh * Ww;
    __builtin_nontemporal_store(o0a, reinterpret_cast<f32x4*>(orow0));
    __builtin_nontemporal_store(o0b, reinterpret_cast<f32x4*>(orow0 + 4));
    __builtin_nontemporal_store(o1a, reinterpret_cast<f32x4*>(orow1));
    __builtin_nontemporal_store(o1b, reinterpret_cast<f32x4*>(orow1 + 4));
}

extern "C" void kernel_launch(void* const* d_in, const int* in_sizes, int n_in,
                              void* d_out, int out_size, void* d_ws, size_t ws_size,
                              hipStream_t stream) {
    const float* in = (const float*)d_in[0];
    float* out = (float*)d_out;

    // total threads = 4 (bc) * 80 (z-pairs) * 192 (y) * 20 (w-chunks)
    const int total  = BC * (Dd / 2) * Hh * (Ww / 8);   // 1,228,800
    const int blocks = total / 256;                     // 4800
    CoeffToValue_kernel<<<blocks, 256, 0, stream>>>(in, out);
}

// Round 6
// 51.237 us; speedup vs baseline: 1.4821x; 1.4484x over previous
//
#include <hip/hip_runtime.h>

// Separable cubic-B-spline coefficient->value filter:
// out = F_D(F_H(F_W(coeff))), 3-tap [1/6, 4/6, 1/6], zero padding.
// Shape: (B*C=4, D=160, H=192, W=160), fp32.
//
// R6: z-column sliding-window. Each thread: 8 w-outputs x ZC=10 z-outputs
// at fixed (bc, y). Double-buffered raw-slice registers give a structural
// one-iteration load->use distance (prefetch slice z+2 while computing z).
// Plain stores (nontemporal inflated WRITE_SIZE 77->98 MB in R5).

typedef float f32x4 __attribute__((ext_vector_type(4)));

static constexpr int Dd = 160;
static constexpr int Hh = 192;
static constexpr int Ww = 160;
static constexpr int BC = 4;
static constexpr int HW = Hh * Ww;

static constexpr float KW1 = 1.0f / 6.0f;
static constexpr float KW0 = 2.0f / 3.0f;

static constexpr int ZC  = 10;        // z outputs per thread
static constexpr int NZC = Dd / ZC;   // 16 chunks

// Load raw slice S (z = z0+S, clamped; OOB handled by zero z-weights) into buf B.
#define LOAD_SLICE(B, S)                                                  \
    do {                                                                  \
        int zs_ = z0 + (S);                                               \
        zs_ = zs_ < 0 ? 0 : (zs_ >= Dd ? Dd - 1 : zs_);                   \
        const float* p_ = base_bc + (size_t)zs_ * HW;                     \
        _Pragma("unroll")                                                 \
        for (int dy_ = 0; dy_ < 3; ++dy_) {                               \
            const float* row_ = p_ + yterm[dy_];                          \
            ra[B][dy_] = *reinterpret_cast<const f32x4*>(row_);           \
            rb[B][dy_] = *reinterpret_cast<const f32x4*>(row_ + 4);       \
            rl[B][dy_] = row_[offL];                                      \
            rr[B][dy_] = row_[offR];                                      \
        }                                                                 \
    } while (0)

// y-filter buf B into yfb[SLOT] (10-wide zy... y-filtered row at w0-1..w0+8).
#define YFILTER(SLOT, B)                                                  \
    do {                                                                  \
        float* yf_ = yfb[SLOT];                                           \
        yf_[0] = mL * (cyw[0] * rl[B][0] + cyw[1] * rl[B][1] +            \
                       cyw[2] * rl[B][2]);                                \
        yf_[9] = mR * (cyw[0] * rr[B][0] + cyw[1] * rr[B][1] +            \
                       cyw[2] * rr[B][2]);                                \
        _Pragma("unroll")                                                 \
        for (int k_ = 0; k_ < 4; ++k_) {                                  \
            yf_[1 + k_] = cyw[0] * ra[B][0][k_] + cyw[1] * ra[B][1][k_] + \
                          cyw[2] * ra[B][2][k_];                          \
            yf_[5 + k_] = cyw[0] * rb[B][0][k_] + cyw[1] * rb[B][1][k_] + \
                          cyw[2] * rb[B][2][k_];                          \
        }                                                                 \
    } while (0)

__global__ __launch_bounds__(256, 2) void CoeffToValue_kernel(
    const float* __restrict__ in, float* __restrict__ out)
{
    const int idx = blockIdx.x * 256 + threadIdx.x;
    const int wc = idx % 20;
    const int r1 = idx / 20;
    const int y  = r1 % Hh;
    const int r2 = r1 / Hh;
    const int zc = r2 % NZC;
    const int bc = r2 / NZC;

    const int z0 = zc * ZC;
    const int w0 = wc * 8;

    // y taps: clamped row offsets, OOB folded into zeroed weights.
    int yterm[3];
    float cyw[3];
    {
        const float wy[3] = {KW1, KW0, KW1};
#pragma unroll
        for (int dy = 0; dy < 3; ++dy) {
            int ys = y + dy - 1;
            const float ok = (ys >= 0 && ys < Hh) ? 1.0f : 0.0f;
            ys = ys < 0 ? 0 : (ys >= Hh ? Hh - 1 : ys);
            yterm[dy] = ys * Ww;
            cyw[dy] = wy[dy] * ok;
        }
    }

    const float* base_bc = in + (size_t)bc * Dd * HW + w0;
    const int offL = (w0 > 0) ? -1 : 0;          // clamped w-edge offsets
    const int offR = (w0 + 8 < Ww) ? 8 : 7;
    const float mL = (w0 > 0) ? 1.0f : 0.0f;     // w-edge zero masks
    const float mR = (w0 + 8 < Ww) ? 1.0f : 0.0f;

    // Double-buffered raw slice (3 y-rows x 10 floats) + 3-slot yf ring.
    f32x4 ra[2][3], rb[2][3];
    float rl[2][3], rr[2][3];
    float yfb[3][10];

    // Prologue. raw[s] lives in buffer s&1 (s=-1 -> buf 1).
    LOAD_SLICE(1, -1);
    LOAD_SLICE(0, 0);
    YFILTER(2, 1);            // slice -1 -> slot 2
    LOAD_SLICE(1, 1);
    YFILTER(0, 0);            // slice  0 -> slot 0

    float* orow = out + (((size_t)bc * Dd + z0) * Hh + y) * Ww + w0;

#pragma unroll
    for (int i = 0; i < ZC; ++i) {
        // Prefetch raw slice i+2 (not needed past slice ZC).
        if (i + 2 <= ZC) {
            if ((i & 1) == 0) { LOAD_SLICE(0, i + 2); }
            else              { LOAD_SLICE(1, i + 2); }
        }
        // y-filter slice i+1 (loaded one iteration ago, buffer (i+1)&1).
        {
            const int sp_ = (i + 1) % 3;
            if (((i + 1) & 1) == 0) { YFILTER(sp_, 0); }
            else                    { YFILTER(sp_, 1); }
        }

        // z-filter (edge slices get zero weight; their clamped data is finite).
        const int z = z0 + i;
        const float czm = (z > 0)      ? KW1 : 0.0f;
        const float czp = (z < Dd - 1) ? KW1 : 0.0f;
        const int sm = (i + 2) % 3;   // slot(i-1)
        const int s0 = i % 3;
        const int sp = (i + 1) % 3;

        float t[10];
#pragma unroll
        for (int j = 0; j < 10; ++j)
            t[j] = fmaf(czm, yfb[sm][j],
                   fmaf(KW0, yfb[s0][j], czp * yfb[sp][j]));

        // w-filter, two aligned float4 stores.
        f32x4 oa, ob;
#pragma unroll
        for (int k = 0; k < 4; ++k) {
            oa[k] = fmaf(KW1, t[k],     fmaf(KW0, t[k + 1], KW1 * t[k + 2]));
            ob[k] = fmaf(KW1, t[k + 4], fmaf(KW0, t[k + 5], KW1 * t[k + 6]));
        }
        *reinterpret_cast<f32x4*>(orow)     = oa;
        *reinterpret_cast<f32x4*>(orow + 4) = ob;
        orow += (size_t)HW;
    }
}

extern "C" void kernel_launch(void* const* d_in, const int* in_sizes, int n_in,
                              void* d_out, int out_size, void* d_ws, size_t ws_size,
                              hipStream_t stream) {
    const float* in = (const float*)d_in[0];
    float* out = (float*)d_out;

    // threads = 4 (bc) * 16 (z-chunks) * 192 (y) * 20 (w-chunks) = 245,760
    const int total  = BC * NZC * Hh * (Ww / 8);
    const int blocks = total / 256;               // 960
    CoeffToValue_kernel<<<blocks, 256, 0, stream>>>(in, out);
}